// Round 1
// baseline (715.875 us; speedup 1.0000x reference)
//
#include <hip/hip_runtime.h>

typedef unsigned short u16;
typedef __attribute__((ext_vector_type(8))) short s16x8;   // 8 bf16 in 4 VGPRs
typedef __attribute__((ext_vector_type(4))) float f32x4;

#define L_SEQ 4096
#define NB    8
#define DIM_  256
#define DI_   512
#define NST   16
#define RLOW  16
#define NCH   32     // chunks
#define CHL   128    // steps per chunk

__device__ __forceinline__ u16 f2bf(float f) {
    unsigned u = __float_as_uint(f);
    unsigned r = u + 0x7fffu + ((u >> 16) & 1u);
    return (u16)(r >> 16);
}
__device__ __forceinline__ float bf2f(u16 h) {
    return __uint_as_float(((unsigned)h) << 16);
}
__device__ __forceinline__ float silu_f(float x) { return x / (1.f + __expf(-x)); }
__device__ __forceinline__ float softplus_f(float x) {
    return (x > 20.f) ? x : __logf(1.f + __expf(x));
}

// ---------------- prep: cast inputs to bf16, precompute A*log2e ----------------
__global__ __launch_bounds__(256) void prep_kernel(
    const float* __restrict__ x, const float* __restrict__ Win,
    const float* __restrict__ cw, const float* __restrict__ xpw,
    const float* __restrict__ Wout, const float* __restrict__ Al,
    u16* __restrict__ xbf, u16* __restrict__ winbf, u16* __restrict__ cwbf,
    u16* __restrict__ xpbf, u16* __restrict__ wobf, float* __restrict__ Af)
{
    long i = (long)blockIdx.x * 256 + threadIdx.x;
    if (i < 8388608)  { xbf[i]  = f2bf(x[i]);   return; }  i -= 8388608;
    if (i < 262144)   { winbf[i] = f2bf(Win[i]); return; }  i -= 262144;
    if (i < 262144)   { cwbf[i] = f2bf(cw[i]);  return; }  i -= 262144;
    if (i < 49152)    { xpbf[i] = f2bf(xpw[i]); return; }  i -= 49152;
    if (i < 131072)   { wobf[i] = f2bf(Wout[i]); return; } i -= 131072;
    if (i < 16384)    { Af[i] = -__expf(Al[i]) * 1.4426950408889634f; }
}

// ---------------- big GEMM: C[M,N] = A[M,K] @ W[N,K]^T, bf16 MFMA ----------------
// 128x128 tile, 4 waves (2x2), each wave 64x64 = 4x4 tiles of 16x16x32.
// EPI 0: in_proj  (cols<512 -> xx_bf raw, cols>=512 -> z_bf = silu)
// EPI 1: conv     (+bias, silu -> u_bf)
// EPI 2: out_proj (fp32 -> of)
template<int EPI>
__global__ __launch_bounds__(256) void gemm128(
    const u16* __restrict__ A, const u16* __restrict__ W, int Kd,
    const float* __restrict__ bias,
    u16* __restrict__ ob0, u16* __restrict__ ob1, float* __restrict__ of)
{
    const int m0 = blockIdx.y * 128;
    const int n0 = blockIdx.x * 128;
    const int tid = threadIdx.x;
    const int wave = tid >> 6, lane = tid & 63;
    const int wr = wave >> 1, wc = wave & 1;
    __shared__ __align__(16) u16 As[128 * 40];
    __shared__ __align__(16) u16 Bs[128 * 40];
    f32x4 acc[4][4] = {};
    const int lrow = tid >> 2;
    const int lk = (tid & 3) * 8;
    const int lm = lane & 15, lq = (lane >> 4) * 8;
    for (int k0 = 0; k0 < Kd; k0 += 32) {
        __syncthreads();
        #pragma unroll
        for (int cc = 0; cc < 2; ++cc) {
            int r = lrow + cc * 64;
            *(s16x8*)&As[r * 40 + lk] = *(const s16x8*)&A[(long)(m0 + r) * Kd + k0 + lk];
            *(s16x8*)&Bs[r * 40 + lk] = *(const s16x8*)&W[(long)(n0 + r) * Kd + k0 + lk];
        }
        __syncthreads();
        s16x8 aF[4], bF[4];
        #pragma unroll
        for (int it = 0; it < 4; ++it)
            aF[it] = *(const s16x8*)&As[(wr * 64 + it * 16 + lm) * 40 + lq];
        #pragma unroll
        for (int jt = 0; jt < 4; ++jt)
            bF[jt] = *(const s16x8*)&Bs[(wc * 64 + jt * 16 + lm) * 40 + lq];
        #pragma unroll
        for (int it = 0; it < 4; ++it)
            #pragma unroll
            for (int jt = 0; jt < 4; ++jt)
                acc[it][jt] = __builtin_amdgcn_mfma_f32_16x16x32_bf16(aF[it], bF[jt], acc[it][jt], 0, 0, 0);
    }
    const int lq4 = (lane >> 4) * 4;
    #pragma unroll
    for (int it = 0; it < 4; ++it)
        #pragma unroll
        for (int jt = 0; jt < 4; ++jt)
            #pragma unroll
            for (int r = 0; r < 4; ++r) {
                int row = m0 + wr * 64 + it * 16 + lq4 + r;
                int col = n0 + wc * 64 + jt * 16 + lm;
                float v = acc[it][jt][r];
                if (EPI == 0) {
                    if (col < 512) ob0[(long)row * 512 + col] = f2bf(v);
                    else           ob1[(long)row * 512 + (col - 512)] = f2bf(silu_f(v));
                } else if (EPI == 1) {
                    v += bias[col];
                    ob0[(long)row * 512 + col] = f2bf(silu_f(v));
                } else {
                    of[(long)row * 256 + col] = v;
                }
            }
}

// ---------------- x_proj GEMM: proj[M,96] = u[M,512] @ xpw[96,512]^T ----------------
// one wave per 16 rows, 6 column tiles, fragments straight from global.
__global__ __launch_bounds__(256) void xproj_gemm(
    const u16* __restrict__ u_bf, const u16* __restrict__ xpw,
    float* __restrict__ proj)
{
    const int wave = threadIdx.x >> 6, lane = threadIdx.x & 63;
    const int m0 = blockIdx.x * 64 + wave * 16;
    const int lm = lane & 15, lq = (lane >> 4) * 8;
    f32x4 acc[6] = {};
    for (int k0 = 0; k0 < 512; k0 += 32) {
        s16x8 aF = *(const s16x8*)&u_bf[(long)(m0 + lm) * 512 + k0 + lq];
        #pragma unroll
        for (int jt = 0; jt < 6; ++jt) {
            s16x8 bF = *(const s16x8*)&xpw[(long)(jt * 16 + lm) * 512 + k0 + lq];
            acc[jt] = __builtin_amdgcn_mfma_f32_16x16x32_bf16(aF, bF, acc[jt], 0, 0, 0);
        }
    }
    const int lq4 = (lane >> 4) * 4;
    #pragma unroll
    for (int jt = 0; jt < 6; ++jt)
        #pragma unroll
        for (int r = 0; r < 4; ++r)
            proj[(long)(m0 + lq4 + r) * 96 + jt * 16 + lm] = acc[jt][r];
}

// ---------------- chunked selective scan ----------------
// PASS 0: per-chunk local scan from h=0, records P[n]=prod(a) and local end-state.
// PASS 1: replay with true initial state (from hinit), emit y per token.
// delta recomputed in-scan: dot16(proj_row[0:16], dt_w) + dt_b -> softplus.
// proj row address is wave-uniform -> scalar loads.
template<int PASS>
__global__ __launch_bounds__(256) void scan_pass(
    const u16* __restrict__ u_bf, const float* __restrict__ proj,
    const float* __restrict__ Af, const float* __restrict__ dtw_g,
    const float* __restrict__ dtb_g, const float* __restrict__ Ds,
    float* __restrict__ Pbuf, float* __restrict__ hloc,
    const float* __restrict__ hinit, u16* __restrict__ ys_bf)
{
    const int bid = blockIdx.x;
    const int c  = bid & (NCH - 1);
    const int t2 = bid >> 5;
    const int dh = t2 & 1;
    const int bk = t2 >> 1;            // b*2+k
    const int k = bk & 1, b = bk >> 1;
    const int d = dh * 256 + threadIdx.x;
    const int kd = k * 512 + d;
    const long ch = (long)bk * 512 + d;

    float A2[16], dtw[16], h[16], P[16];
    #pragma unroll
    for (int n = 0; n < 16; ++n) A2[n] = Af[(long)kd * 16 + n];
    #pragma unroll
    for (int r = 0; r < 16; ++r) dtw[r] = dtw_g[(long)kd * 16 + r];
    const float dtb = dtb_g[kd];
    const float Dv = (PASS == 1) ? Ds[kd] : 0.f;
    if (PASS == 0) {
        #pragma unroll
        for (int n = 0; n < 16; ++n) { h[n] = 0.f; P[n] = 1.f; }
    } else {
        #pragma unroll
        for (int n = 0; n < 16; ++n) h[n] = hinit[ch * (NCH * 16) + c * 16 + n];
    }

    const int t0 = c * CHL;
    for (int s = 0; s < CHL; ++s) {
        int t = t0 + s;
        int m = k ? (L_SEQ - 1 - t) : t;
        long row = (long)b * L_SEQ + m;
        const float* pr = proj + row * 96 + k * 48;   // wave-uniform
        float dt = dtb;
        #pragma unroll
        for (int r = 0; r < 16; ++r) dt = fmaf(pr[r], dtw[r], dt);
        float delta = softplus_f(dt);
        float uu = bf2f(u_bf[row * 512 + d]);
        float du = delta * uu;
        float y = 0.f;
        #pragma unroll
        for (int n = 0; n < 16; ++n) {
            float a = exp2f(delta * A2[n]);
            h[n] = fmaf(a, h[n], du * pr[16 + n]);
            if (PASS == 0) P[n] *= a;
            else           y = fmaf(h[n], pr[32 + n], y);
        }
        if (PASS == 1) {
            y = fmaf(Dv, uu, y);
            ys_bf[row * 1024 + (long)k * 512 + d] = f2bf(y);
        }
    }
    if (PASS == 0) {
        long base = ch * (NCH * 16) + c * 16;
        #pragma unroll
        for (int n = 0; n < 16; ++n) { Pbuf[base + n] = P[n]; hloc[base + n] = h[n]; }
    }
}

// pass 2: chain the chunk summaries. thread = (channel, n)
__global__ __launch_bounds__(256) void scan_pass2(
    const float* __restrict__ Pbuf, const float* __restrict__ hloc,
    float* __restrict__ hinit)
{
    int gid = blockIdx.x * 256 + threadIdx.x;      // 131072
    long ch = gid >> 4;
    int n = gid & 15;
    long base = ch * (NCH * 16) + n;
    float h = 0.f;
    for (int c = 0; c < NCH; ++c) {
        hinit[base + c * 16] = h;
        h = Pbuf[base + c * 16] * h + hloc[base + c * 16];
    }
}

// ---------------- merge + LayerNorm + gate ----------------
__global__ __launch_bounds__(256) void ln_gate(
    const u16* __restrict__ ys_bf, const u16* __restrict__ z_bf,
    const float* __restrict__ ln_w, const float* __restrict__ ln_b,
    u16* __restrict__ yln)
{
    const int row = blockIdx.x;
    const int tid = threadIdx.x;
    const long b0 = (long)row * 1024;
    float v0 = bf2f(ys_bf[b0 + tid])       + bf2f(ys_bf[b0 + 512 + tid]);
    float v1 = bf2f(ys_bf[b0 + 256 + tid]) + bf2f(ys_bf[b0 + 768 + tid]);
    float s = v0 + v1;
    float q = v0 * v0 + v1 * v1;
    __shared__ float red[8];
    const int wv = tid >> 6, ln = tid & 63;
    #pragma unroll
    for (int off = 32; off > 0; off >>= 1) {
        s += __shfl_down(s, off);
        q += __shfl_down(q, off);
    }
    if (ln == 0) { red[wv] = s; red[4 + wv] = q; }
    __syncthreads();
    if (tid == 0) {
        float S = red[0] + red[1] + red[2] + red[3];
        float Q = red[4] + red[5] + red[6] + red[7];
        float mu = S * (1.f / 512.f);
        float var = Q * (1.f / 512.f) - mu * mu;
        red[0] = mu;
        red[1] = rsqrtf(var + 1e-5f);
    }
    __syncthreads();
    const float mu = red[0], rstd = red[1];
    const long zb = (long)row * 512;
    float o0 = (v0 - mu) * rstd * ln_w[tid] + ln_b[tid];
    float o1 = (v1 - mu) * rstd * ln_w[tid + 256] + ln_b[tid + 256];
    yln[zb + tid]       = f2bf(o0 * bf2f(z_bf[zb + tid]));
    yln[zb + 256 + tid] = f2bf(o1 * bf2f(z_bf[zb + 256 + tid]));
}

// ---------------- host launcher ----------------
extern "C" void kernel_launch(void* const* d_in, const int* in_sizes, int n_in,
                              void* d_out, int out_size, void* d_ws, size_t ws_size,
                              hipStream_t stream)
{
    const float* x      = (const float*)d_in[0];
    const float* W_in   = (const float*)d_in[1];
    const float* conv_w = (const float*)d_in[2];
    const float* conv_b = (const float*)d_in[3];
    const float* xpw    = (const float*)d_in[4];
    const float* dt_w   = (const float*)d_in[5];
    const float* dt_b   = (const float*)d_in[6];
    const float* A_logs = (const float*)d_in[7];
    const float* Ds     = (const float*)d_in[8];
    const float* ln_w   = (const float*)d_in[9];
    const float* ln_b   = (const float*)d_in[10];
    const float* W_out  = (const float*)d_in[11];

    char* w = (char*)d_ws;
    u16*   x_bf   = (u16*)  (w + 0);            // 16,777,216
    u16*   xx_bf  = (u16*)  (w + 16777216);     // 33,554,432
    u16*   z_bf   = (u16*)  (w + 50331648);     // 33,554,432
    u16*   u_bf   = (u16*)  (w + 83886080);     // 33,554,432
    u16*   yln_bf = (u16*)  (w + 117440512);    // 33,554,432
    u16*   win_bf = (u16*)  (w + 150994944);    // 524,288
    u16*   cw_bf  = (u16*)  (w + 151519232);    // 524,288
    u16*   xp_bf  = (u16*)  (w + 152043520);    // 98,304
    u16*   wo_bf  = (u16*)  (w + 152141824);    // 262,144
    float* Af     = (float*)(w + 152403968);    // 65,536
    float* proj   = (float*)(w + 152469504);    // 12,582,912
    u16*   ys_bf  = (u16*)  (w + 165052416);    // 33,554,432
    float* Pbuf   = (float*)(w + 198606848);    // 16,777,216
    float* hloc   = (float*)(w + 215384064);    // 16,777,216
    float* hinit  = (float*)(w + 232161280);    // 16,777,216
    // total: 248,938,496 bytes

    prep_kernel<<<35584, 256, 0, stream>>>(x, W_in, conv_w, xpw, W_out, A_logs,
                                           x_bf, win_bf, cw_bf, xp_bf, wo_bf, Af);

    // in_proj: [32768,256] @ [1024,256]^T
    gemm128<0><<<dim3(8, 256), 256, 0, stream>>>(x_bf, win_bf, 256, nullptr, xx_bf, z_bf, nullptr);
    // conv1x1 + bias + silu: [32768,512] @ [512,512]^T
    gemm128<1><<<dim3(4, 256), 256, 0, stream>>>(xx_bf, cw_bf, 512, conv_b, u_bf, nullptr, nullptr);
    // x_proj: [32768,512] @ [96,512]^T
    xproj_gemm<<<512, 256, 0, stream>>>(u_bf, xp_bf, proj);

    // scan
    scan_pass<0><<<1024, 256, 0, stream>>>(u_bf, proj, Af, dt_w, dt_b, Ds,
                                           Pbuf, hloc, nullptr, nullptr);
    scan_pass2<<<512, 256, 0, stream>>>(Pbuf, hloc, hinit);
    scan_pass<1><<<1024, 256, 0, stream>>>(u_bf, proj, Af, dt_w, dt_b, Ds,
                                           nullptr, nullptr, hinit, ys_bf);

    // merge + LN + gate
    ln_gate<<<32768, 256, 0, stream>>>(ys_bf, z_bf, ln_w, ln_b, yln_bf);
    // out_proj: [32768,512] @ [256,512]^T -> d_out
    gemm128<2><<<dim3(2, 256), 256, 0, stream>>>(yln_bf, wo_bf, 512, nullptr, nullptr, nullptr, (float*)d_out);
}

// Round 2
// 690.913 us; speedup vs baseline: 1.0361x; 1.0361x over previous
//
#include <hip/hip_runtime.h>

typedef unsigned short u16;
typedef __attribute__((ext_vector_type(8))) short s16x8;   // 8 bf16 in 4 VGPRs
typedef __attribute__((ext_vector_type(4))) float f32x4;

#define L_SEQ 4096
#define NB    8
#define DIM_  256
#define DI_   512
#define NST   16
#define RLOW  16
#define NCH   32     // chunks
#define CHL   128    // steps per chunk

__device__ __forceinline__ u16 f2bf(float f) {
    unsigned u = __float_as_uint(f);
    unsigned r = u + 0x7fffu + ((u >> 16) & 1u);
    return (u16)(r >> 16);
}
__device__ __forceinline__ float bf2f(u16 h) {
    return __uint_as_float(((unsigned)h) << 16);
}
__device__ __forceinline__ float silu_f(float x) { return x / (1.f + __expf(-x)); }
__device__ __forceinline__ float softplus_f(float x) {
    return (x > 20.f) ? x : __logf(1.f + __expf(x));
}

// ---------------- prep: cast inputs to bf16, precompute A*log2e ----------------
__global__ __launch_bounds__(256) void prep_kernel(
    const float* __restrict__ x, const float* __restrict__ Win,
    const float* __restrict__ cw, const float* __restrict__ xpw,
    const float* __restrict__ Wout, const float* __restrict__ Al,
    u16* __restrict__ xbf, u16* __restrict__ winbf, u16* __restrict__ cwbf,
    u16* __restrict__ xpbf, u16* __restrict__ wobf, float* __restrict__ Af)
{
    long i = (long)blockIdx.x * 256 + threadIdx.x;
    if (i < 8388608)  { xbf[i]  = f2bf(x[i]);   return; }  i -= 8388608;
    if (i < 262144)   { winbf[i] = f2bf(Win[i]); return; }  i -= 262144;
    if (i < 262144)   { cwbf[i] = f2bf(cw[i]);  return; }  i -= 262144;
    if (i < 49152)    { xpbf[i] = f2bf(xpw[i]); return; }  i -= 49152;
    if (i < 131072)   { wobf[i] = f2bf(Wout[i]); return; } i -= 131072;
    if (i < 16384)    { Af[i] = -__expf(Al[i]) * 1.4426950408889634f; }
}

// ---------------- big GEMM: C[M,N] = A[M,K] @ W[N,K]^T, bf16 MFMA ----------------
template<int EPI>
__global__ __launch_bounds__(256, 2) void gemm128(
    const u16* __restrict__ A, const u16* __restrict__ W, int Kd,
    const float* __restrict__ bias,
    u16* __restrict__ ob0, u16* __restrict__ ob1, float* __restrict__ of)
{
    const int m0 = blockIdx.y * 128;
    const int n0 = blockIdx.x * 128;
    const int tid = threadIdx.x;
    const int wave = tid >> 6, lane = tid & 63;
    const int wr = wave >> 1, wc = wave & 1;
    __shared__ __align__(16) u16 As[128 * 40];
    __shared__ __align__(16) u16 Bs[128 * 40];
    f32x4 acc[4][4] = {};
    const int lrow = tid >> 2;
    const int lk = (tid & 3) * 8;
    const int lm = lane & 15, lq = (lane >> 4) * 8;
    for (int k0 = 0; k0 < Kd; k0 += 32) {
        __syncthreads();
        #pragma unroll
        for (int cc = 0; cc < 2; ++cc) {
            int r = lrow + cc * 64;
            *(s16x8*)&As[r * 40 + lk] = *(const s16x8*)&A[(long)(m0 + r) * Kd + k0 + lk];
            *(s16x8*)&Bs[r * 40 + lk] = *(const s16x8*)&W[(long)(n0 + r) * Kd + k0 + lk];
        }
        __syncthreads();
        s16x8 aF[4], bF[4];
        #pragma unroll
        for (int it = 0; it < 4; ++it)
            aF[it] = *(const s16x8*)&As[(wr * 64 + it * 16 + lm) * 40 + lq];
        #pragma unroll
        for (int jt = 0; jt < 4; ++jt)
            bF[jt] = *(const s16x8*)&Bs[(wc * 64 + jt * 16 + lm) * 40 + lq];
        #pragma unroll
        for (int it = 0; it < 4; ++it)
            #pragma unroll
            for (int jt = 0; jt < 4; ++jt)
                acc[it][jt] = __builtin_amdgcn_mfma_f32_16x16x32_bf16(aF[it], bF[jt], acc[it][jt], 0, 0, 0);
    }
    const int lq4 = (lane >> 4) * 4;
    #pragma unroll
    for (int it = 0; it < 4; ++it)
        #pragma unroll
        for (int jt = 0; jt < 4; ++jt)
            #pragma unroll
            for (int r = 0; r < 4; ++r) {
                int row = m0 + wr * 64 + it * 16 + lq4 + r;
                int col = n0 + wc * 64 + jt * 16 + lm;
                float v = acc[it][jt][r];
                if (EPI == 0) {
                    if (col < 512) ob0[(long)row * 512 + col] = f2bf(v);
                    else           ob1[(long)row * 512 + (col - 512)] = f2bf(silu_f(v));
                } else if (EPI == 1) {
                    v += bias[col];
                    ob0[(long)row * 512 + col] = f2bf(silu_f(v));
                } else {
                    of[(long)row * 256 + col] = v;
                }
            }
}

// ---------------- x_proj GEMM: proj[M,96] = u[M,512] @ xpw[96,512]^T ----------------
__global__ __launch_bounds__(256, 4) void xproj_gemm(
    const u16* __restrict__ u_bf, const u16* __restrict__ xpw,
    float* __restrict__ proj)
{
    const int wave = threadIdx.x >> 6, lane = threadIdx.x & 63;
    const int m0 = blockIdx.x * 64 + wave * 16;
    const int lm = lane & 15, lq = (lane >> 4) * 8;
    f32x4 acc[6] = {};
    for (int k0 = 0; k0 < 512; k0 += 32) {
        s16x8 aF = *(const s16x8*)&u_bf[(long)(m0 + lm) * 512 + k0 + lq];
        #pragma unroll
        for (int jt = 0; jt < 6; ++jt) {
            s16x8 bF = *(const s16x8*)&xpw[(long)(jt * 16 + lm) * 512 + k0 + lq];
            acc[jt] = __builtin_amdgcn_mfma_f32_16x16x32_bf16(aF, bF, acc[jt], 0, 0, 0);
        }
    }
    const int lq4 = (lane >> 4) * 4;
    #pragma unroll
    for (int jt = 0; jt < 6; ++jt)
        #pragma unroll
        for (int r = 0; r < 4; ++r)
            proj[(long)(m0 + lq4 + r) * 96 + jt * 16 + lm] = acc[jt][r];
}

// ---------------- chunked selective scan ----------------
// PASS 0: local scan from h=0; records sum(delta) -> P[n]=exp2(A[n]*sum) and end state.
// PASS 1: replay with true initial state (hinit), emit y per token.
// proj row address is wave-uniform -> scalar loads (s_load_dwordx16).
template<int PASS>
__global__ __launch_bounds__(256, 4) void scan_pass(
    const u16* __restrict__ u_bf, const float* __restrict__ proj,
    const float* __restrict__ Af, const float* __restrict__ dtw_g,
    const float* __restrict__ dtb_g, const float* __restrict__ Ds,
    float* __restrict__ Pbuf, float* __restrict__ hloc,
    const float* __restrict__ hinit, u16* __restrict__ ys_bf)
{
    const int bid = blockIdx.x;
    const int c  = bid & (NCH - 1);
    const int t2 = bid >> 5;
    const int dh = t2 & 1;
    const int bk = t2 >> 1;            // b*2+k
    const int k = bk & 1, b = bk >> 1;
    const int d = dh * 256 + threadIdx.x;
    const int kd = k * 512 + d;
    const long ch = (long)bk * 512 + d;

    float A2[16], dtw[16], h[16];
    #pragma unroll
    for (int n = 0; n < 16; ++n) A2[n] = Af[(long)kd * 16 + n];
    #pragma unroll
    for (int r = 0; r < 16; ++r) dtw[r] = dtw_g[(long)kd * 16 + r];
    const float dtb = dtb_g[kd];
    float Dv = 0.f;
    float sdelta = 0.f;
    if (PASS == 0) {
        #pragma unroll
        for (int n = 0; n < 16; ++n) h[n] = 0.f;
    } else {
        Dv = Ds[kd];
        #pragma unroll
        for (int n = 0; n < 16; ++n) h[n] = hinit[ch * (NCH * 16) + c * 16 + n];
    }

    const int t0 = c * CHL;
    const int m0r = k ? (L_SEQ - 1 - t0) : t0;
    const int stp = k ? -1 : 1;
    const long row0 = (long)b * L_SEQ + m0r;
    const float* pr = proj + row0 * 96 + k * 48;      // wave-uniform
    const u16* up = u_bf + row0 * 512 + d;
    u16* yp = (PASS == 1) ? (ys_bf + row0 * 1024 + (long)k * 512 + d) : nullptr;
    const long pstep = (long)stp * 96;
    const long ustep = (long)stp * 512;
    const long ystep = (long)stp * 1024;

    for (int s = 0; s < CHL; ++s) {
        float prv[48];
        #pragma unroll
        for (int i = 0; i < 48; ++i) prv[i] = pr[i];
        float dt = dtb;
        #pragma unroll
        for (int r = 0; r < 16; ++r) dt = fmaf(prv[r], dtw[r], dt);
        float delta = softplus_f(dt);
        float uu = bf2f(*up);
        float du = delta * uu;
        if (PASS == 0) {
            sdelta += delta;
            #pragma unroll
            for (int n = 0; n < 16; ++n) {
                float a = exp2f(delta * A2[n]);
                h[n] = fmaf(a, h[n], du * prv[16 + n]);
            }
        } else {
            float y = 0.f;
            #pragma unroll
            for (int n = 0; n < 16; ++n) {
                float a = exp2f(delta * A2[n]);
                h[n] = fmaf(a, h[n], du * prv[16 + n]);
                y = fmaf(h[n], prv[32 + n], y);
            }
            y = fmaf(Dv, uu, y);
            *yp = f2bf(y);
            yp += ystep;
        }
        pr += pstep;
        up += ustep;
    }
    if (PASS == 0) {
        long base = ch * (NCH * 16) + c * 16;
        #pragma unroll
        for (int n = 0; n < 16; ++n) {
            Pbuf[base + n] = exp2f(A2[n] * sdelta);
            hloc[base + n] = h[n];
        }
    }
}

// pass 2: chain the chunk summaries. thread = (channel, n)
__global__ __launch_bounds__(256) void scan_pass2(
    const float* __restrict__ Pbuf, const float* __restrict__ hloc,
    float* __restrict__ hinit)
{
    int gid = blockIdx.x * 256 + threadIdx.x;      // 131072
    long ch = gid >> 4;
    int n = gid & 15;
    long base = ch * (NCH * 16) + n;
    float h = 0.f;
    for (int c = 0; c < NCH; ++c) {
        hinit[base + c * 16] = h;
        h = Pbuf[base + c * 16] * h + hloc[base + c * 16];
    }
}

// ---------------- merge + LayerNorm + gate ----------------
__global__ __launch_bounds__(256) void ln_gate(
    const u16* __restrict__ ys_bf, const u16* __restrict__ z_bf,
    const float* __restrict__ ln_w, const float* __restrict__ ln_b,
    u16* __restrict__ yln)
{
    const int row = blockIdx.x;
    const int tid = threadIdx.x;
    const long b0 = (long)row * 1024;
    float v0 = bf2f(ys_bf[b0 + tid])       + bf2f(ys_bf[b0 + 512 + tid]);
    float v1 = bf2f(ys_bf[b0 + 256 + tid]) + bf2f(ys_bf[b0 + 768 + tid]);
    float s = v0 + v1;
    float q = v0 * v0 + v1 * v1;
    __shared__ float red[8];
    const int wv = tid >> 6, ln = tid & 63;
    #pragma unroll
    for (int off = 32; off > 0; off >>= 1) {
        s += __shfl_down(s, off);
        q += __shfl_down(q, off);
    }
    if (ln == 0) { red[wv] = s; red[4 + wv] = q; }
    __syncthreads();
    if (tid == 0) {
        float S = red[0] + red[1] + red[2] + red[3];
        float Q = red[4] + red[5] + red[6] + red[7];
        float mu = S * (1.f / 512.f);
        float var = Q * (1.f / 512.f) - mu * mu;
        red[0] = mu;
        red[1] = rsqrtf(var + 1e-5f);
    }
    __syncthreads();
    const float mu = red[0], rstd = red[1];
    const long zb = (long)row * 512;
    float o0 = (v0 - mu) * rstd * ln_w[tid] + ln_b[tid];
    float o1 = (v1 - mu) * rstd * ln_w[tid + 256] + ln_b[tid + 256];
    yln[zb + tid]       = f2bf(o0 * bf2f(z_bf[zb + tid]));
    yln[zb + 256 + tid] = f2bf(o1 * bf2f(z_bf[zb + 256 + tid]));
}

// ---------------- host launcher ----------------
extern "C" void kernel_launch(void* const* d_in, const int* in_sizes, int n_in,
                              void* d_out, int out_size, void* d_ws, size_t ws_size,
                              hipStream_t stream)
{
    const float* x      = (const float*)d_in[0];
    const float* W_in   = (const float*)d_in[1];
    const float* conv_w = (const float*)d_in[2];
    const float* conv_b = (const float*)d_in[3];
    const float* xpw    = (const float*)d_in[4];
    const float* dt_w   = (const float*)d_in[5];
    const float* dt_b   = (const float*)d_in[6];
    const float* A_logs = (const float*)d_in[7];
    const float* Ds     = (const float*)d_in[8];
    const float* ln_w   = (const float*)d_in[9];
    const float* ln_b   = (const float*)d_in[10];
    const float* W_out  = (const float*)d_in[11];

    char* w = (char*)d_ws;
    u16*   x_bf   = (u16*)  (w + 0);            // 16,777,216
    u16*   xx_bf  = (u16*)  (w + 16777216);     // 33,554,432
    u16*   z_bf   = (u16*)  (w + 50331648);     // 33,554,432
    u16*   u_bf   = (u16*)  (w + 83886080);     // 33,554,432
    u16*   yln_bf = (u16*)  (w + 117440512);    // 33,554,432
    u16*   win_bf = (u16*)  (w + 150994944);    // 524,288
    u16*   cw_bf  = (u16*)  (w + 151519232);    // 524,288
    u16*   xp_bf  = (u16*)  (w + 152043520);    // 98,304
    u16*   wo_bf  = (u16*)  (w + 152141824);    // 262,144
    float* Af     = (float*)(w + 152403968);    // 65,536
    float* proj   = (float*)(w + 152469504);    // 12,582,912
    u16*   ys_bf  = (u16*)  (w + 165052416);    // 33,554,432
    float* Pbuf   = (float*)(w + 198606848);    // 16,777,216
    float* hloc   = (float*)(w + 215384064);    // 16,777,216
    float* hinit  = (float*)(w + 232161280);    // 16,777,216
    // total: 248,938,496 bytes

    prep_kernel<<<35584, 256, 0, stream>>>(x, W_in, conv_w, xpw, W_out, A_logs,
                                           x_bf, win_bf, cw_bf, xp_bf, wo_bf, Af);

    // in_proj: [32768,256] @ [1024,256]^T
    gemm128<0><<<dim3(8, 256), 256, 0, stream>>>(x_bf, win_bf, 256, nullptr, xx_bf, z_bf, nullptr);
    // conv1x1 + bias + silu: [32768,512] @ [512,512]^T
    gemm128<1><<<dim3(4, 256), 256, 0, stream>>>(xx_bf, cw_bf, 512, conv_b, u_bf, nullptr, nullptr);
    // x_proj: [32768,512] @ [96,512]^T
    xproj_gemm<<<512, 256, 0, stream>>>(u_bf, xp_bf, proj);

    // scan
    scan_pass<0><<<1024, 256, 0, stream>>>(u_bf, proj, Af, dt_w, dt_b, Ds,
                                           Pbuf, hloc, nullptr, nullptr);
    scan_pass2<<<512, 256, 0, stream>>>(Pbuf, hloc, hinit);
    scan_pass<1><<<1024, 256, 0, stream>>>(u_bf, proj, Af, dt_w, dt_b, Ds,
                                           nullptr, nullptr, hinit, ys_bf);

    // merge + LN + gate
    ln_gate<<<32768, 256, 0, stream>>>(ys_bf, z_bf, ln_w, ln_b, yln_bf);
    // out_proj: [32768,512] @ [256,512]^T -> d_out
    gemm128<2><<<dim3(2, 256), 256, 0, stream>>>(yln_bf, wo_bf, 512, nullptr, nullptr, nullptr, (float*)d_out);
}

// Round 3
// 656.166 us; speedup vs baseline: 1.0910x; 1.0530x over previous
//
#include <hip/hip_runtime.h>

typedef unsigned short u16;
typedef __attribute__((ext_vector_type(8))) short s16x8;   // 8 bf16 in 4 VGPRs
typedef __attribute__((ext_vector_type(4))) float f32x4;

#define L_SEQ 4096
#define NB    8
#define DIM_  256
#define DI_   512
#define NST   16
#define RLOW  16
#define NCH   32     // chunks
#define CHL   128    // steps per chunk

__device__ __forceinline__ u16 f2bf(float f) {
    unsigned u = __float_as_uint(f);
    unsigned r = u + 0x7fffu + ((u >> 16) & 1u);
    return (u16)(r >> 16);
}
__device__ __forceinline__ float bf2f(u16 h) {
    return __uint_as_float(((unsigned)h) << 16);
}
__device__ __forceinline__ float silu_f(float x) { return x / (1.f + __expf(-x)); }
__device__ __forceinline__ float softplus_f(float x) {
    return (x > 20.f) ? x : __logf(1.f + __expf(x));
}

// ---------------- prep: cast inputs to bf16, precompute A*log2e ----------------
__global__ __launch_bounds__(256) void prep_kernel(
    const float* __restrict__ x, const float* __restrict__ Win,
    const float* __restrict__ cw, const float* __restrict__ xpw,
    const float* __restrict__ Wout, const float* __restrict__ Al,
    u16* __restrict__ xbf, u16* __restrict__ winbf, u16* __restrict__ cwbf,
    u16* __restrict__ xpbf, u16* __restrict__ wobf, float* __restrict__ Af)
{
    long i = (long)blockIdx.x * 256 + threadIdx.x;
    if (i < 8388608)  { xbf[i]  = f2bf(x[i]);   return; }  i -= 8388608;
    if (i < 262144)   { winbf[i] = f2bf(Win[i]); return; }  i -= 262144;
    if (i < 262144)   { cwbf[i] = f2bf(cw[i]);  return; }  i -= 262144;
    if (i < 49152)    { xpbf[i] = f2bf(xpw[i]); return; }  i -= 49152;
    if (i < 131072)   { wobf[i] = f2bf(Wout[i]); return; } i -= 131072;
    if (i < 16384)    { Af[i] = -__expf(Al[i]) * 1.4426950408889634f; }
}

// ---------------- big GEMM: C[M,N] = A[M,K] @ W[N,K]^T, bf16 MFMA ----------------
template<int EPI>
__global__ __launch_bounds__(256, 2) void gemm128(
    const u16* __restrict__ A, const u16* __restrict__ W, int Kd,
    const float* __restrict__ bias,
    u16* __restrict__ ob0, u16* __restrict__ ob1, float* __restrict__ of)
{
    const int m0 = blockIdx.y * 128;
    const int n0 = blockIdx.x * 128;
    const int tid = threadIdx.x;
    const int wave = tid >> 6, lane = tid & 63;
    const int wr = wave >> 1, wc = wave & 1;
    __shared__ __align__(16) u16 As[128 * 40];
    __shared__ __align__(16) u16 Bs[128 * 40];
    f32x4 acc[4][4] = {};
    const int lrow = tid >> 2;
    const int lk = (tid & 3) * 8;
    const int lm = lane & 15, lq = (lane >> 4) * 8;
    for (int k0 = 0; k0 < Kd; k0 += 32) {
        __syncthreads();
        #pragma unroll
        for (int cc = 0; cc < 2; ++cc) {
            int r = lrow + cc * 64;
            *(s16x8*)&As[r * 40 + lk] = *(const s16x8*)&A[(long)(m0 + r) * Kd + k0 + lk];
            *(s16x8*)&Bs[r * 40 + lk] = *(const s16x8*)&W[(long)(n0 + r) * Kd + k0 + lk];
        }
        __syncthreads();
        s16x8 aF[4], bF[4];
        #pragma unroll
        for (int it = 0; it < 4; ++it)
            aF[it] = *(const s16x8*)&As[(wr * 64 + it * 16 + lm) * 40 + lq];
        #pragma unroll
        for (int jt = 0; jt < 4; ++jt)
            bF[jt] = *(const s16x8*)&Bs[(wc * 64 + jt * 16 + lm) * 40 + lq];
        #pragma unroll
        for (int it = 0; it < 4; ++it)
            #pragma unroll
            for (int jt = 0; jt < 4; ++jt)
                acc[it][jt] = __builtin_amdgcn_mfma_f32_16x16x32_bf16(aF[it], bF[jt], acc[it][jt], 0, 0, 0);
    }
    const int lq4 = (lane >> 4) * 4;
    #pragma unroll
    for (int it = 0; it < 4; ++it)
        #pragma unroll
        for (int jt = 0; jt < 4; ++jt)
            #pragma unroll
            for (int r = 0; r < 4; ++r) {
                int row = m0 + wr * 64 + it * 16 + lq4 + r;
                int col = n0 + wc * 64 + jt * 16 + lm;
                float v = acc[it][jt][r];
                if (EPI == 0) {
                    if (col < 512) ob0[(long)row * 512 + col] = f2bf(v);
                    else           ob1[(long)row * 512 + (col - 512)] = f2bf(silu_f(v));
                } else if (EPI == 1) {
                    v += bias[col];
                    ob0[(long)row * 512 + col] = f2bf(silu_f(v));
                } else {
                    of[(long)row * 256 + col] = v;
                }
            }
}

// ---------------- x_proj GEMM: proj[M,96] = u[M,512] @ xpw[96,512]^T ----------------
__global__ __launch_bounds__(256, 4) void xproj_gemm(
    const u16* __restrict__ u_bf, const u16* __restrict__ xpw,
    float* __restrict__ proj)
{
    const int wave = threadIdx.x >> 6, lane = threadIdx.x & 63;
    const int m0 = blockIdx.x * 64 + wave * 16;
    const int lm = lane & 15, lq = (lane >> 4) * 8;
    f32x4 acc[6] = {};
    for (int k0 = 0; k0 < 512; k0 += 32) {
        s16x8 aF = *(const s16x8*)&u_bf[(long)(m0 + lm) * 512 + k0 + lq];
        #pragma unroll
        for (int jt = 0; jt < 6; ++jt) {
            s16x8 bF = *(const s16x8*)&xpw[(long)(jt * 16 + lm) * 512 + k0 + lq];
            acc[jt] = __builtin_amdgcn_mfma_f32_16x16x32_bf16(aF, bF, acc[jt], 0, 0, 0);
        }
    }
    const int lq4 = (lane >> 4) * 4;
    #pragma unroll
    for (int jt = 0; jt < 6; ++jt)
        #pragma unroll
        for (int r = 0; r < 4; ++r)
            proj[(long)(m0 + lq4 + r) * 96 + jt * 16 + lm] = acc[jt][r];
}

// ---------------- chunked selective scan ----------------
// PASS 0: local scan from h=0; records sum(delta) -> P[n]=exp2(A[n]*sum) and end state.
// PASS 1: replay with true initial state (hinit), emit y per token.
// State held in explicit f32x4 registers; waves_per_eu(4,4) pins the register
// budget to 128 VGPRs so the compiler keeps state resident instead of
// rematerializing loads (round-1/2 pathology: VGPR_Count=32, ~80 re-loads/step).
template<int PASS>
__global__ __launch_bounds__(256) __attribute__((amdgpu_waves_per_eu(4, 4)))
void scan_pass(
    const u16* __restrict__ u_bf, const float* __restrict__ proj,
    const float* __restrict__ Af, const float* __restrict__ dtw_g,
    const float* __restrict__ dtb_g, const float* __restrict__ Ds,
    float* __restrict__ Pbuf, float* __restrict__ hloc,
    const float* __restrict__ hinit, u16* __restrict__ ys_bf)
{
    const int bid = blockIdx.x;
    const int c  = bid & (NCH - 1);
    const int t2 = bid >> 5;
    const int dh = t2 & 1;
    const int bk = t2 >> 1;            // b*2+k
    const int k = bk & 1, b = bk >> 1;
    const int d = dh * 256 + threadIdx.x;
    const int kd = k * 512 + d;
    const long ch = (long)bk * 512 + d;

    f32x4 A2[4], dtw[4], h[4];
    {
        const f32x4* Ap = (const f32x4*)(Af + (long)kd * 16);
        const f32x4* Wp = (const f32x4*)(dtw_g + (long)kd * 16);
        #pragma unroll
        for (int i = 0; i < 4; ++i) { A2[i] = Ap[i]; dtw[i] = Wp[i]; }
    }
    const float dtb = dtb_g[kd];
    float Dv = 0.f;
    float sdelta = 0.f;
    if (PASS == 0) {
        #pragma unroll
        for (int i = 0; i < 4; ++i) h[i] = (f32x4){0.f, 0.f, 0.f, 0.f};
    } else {
        Dv = Ds[kd];
        const f32x4* Hp = (const f32x4*)(hinit + ch * (NCH * 16) + c * 16);
        #pragma unroll
        for (int i = 0; i < 4; ++i) h[i] = Hp[i];
    }

    const int t0 = c * CHL;
    const int m0r = k ? (L_SEQ - 1 - t0) : t0;
    const int stp = k ? -1 : 1;
    const long row0 = (long)b * L_SEQ + m0r;
    const f32x4* pp = (const f32x4*)(proj + row0 * 96 + k * 48);  // 16B-aligned
    const u16* up = u_bf + row0 * 512 + d;
    u16* yp = (PASS == 1) ? (ys_bf + row0 * 1024 + (long)k * 512 + d) : nullptr;
    const long pstep = (long)stp * 24;     // 96 floats = 24 f32x4
    const long ustep = (long)stp * 512;
    const long ystep = (long)stp * 1024;

    for (int s = 0; s < CHL; ++s) {
        const int NP = (PASS == 0) ? 8 : 12;
        f32x4 p[12];
        #pragma unroll
        for (int i = 0; i < NP; ++i) p[i] = pp[i];
        float dt = dtb;
        #pragma unroll
        for (int i = 0; i < 4; ++i)
            #pragma unroll
            for (int j = 0; j < 4; ++j)
                dt = fmaf(p[i][j], dtw[i][j], dt);
        float delta = softplus_f(dt);
        float uu = bf2f(*up);
        float du = delta * uu;
        if (PASS == 0) {
            sdelta += delta;
            #pragma unroll
            for (int i = 0; i < 4; ++i)
                #pragma unroll
                for (int j = 0; j < 4; ++j) {
                    float a = exp2f(delta * A2[i][j]);
                    h[i][j] = fmaf(a, h[i][j], du * p[4 + i][j]);
                }
        } else {
            float y = 0.f;
            #pragma unroll
            for (int i = 0; i < 4; ++i)
                #pragma unroll
                for (int j = 0; j < 4; ++j) {
                    float a = exp2f(delta * A2[i][j]);
                    float hv = fmaf(a, h[i][j], du * p[4 + i][j]);
                    h[i][j] = hv;
                    y = fmaf(hv, p[8 + i][j], y);
                }
            y = fmaf(Dv, uu, y);
            *yp = f2bf(y);
            yp += ystep;
        }
        pp += pstep;
        up += ustep;
    }
    if (PASS == 0) {
        f32x4* Pp = (f32x4*)(Pbuf + ch * (NCH * 16) + c * 16);
        f32x4* Hp = (f32x4*)(hloc + ch * (NCH * 16) + c * 16);
        #pragma unroll
        for (int i = 0; i < 4; ++i) {
            f32x4 pe;
            #pragma unroll
            for (int j = 0; j < 4; ++j) pe[j] = exp2f(A2[i][j] * sdelta);
            Pp[i] = pe;
            Hp[i] = h[i];
        }
    }
}

// pass 2: chain the chunk summaries. thread = (channel, n)
__global__ __launch_bounds__(256) void scan_pass2(
    const float* __restrict__ Pbuf, const float* __restrict__ hloc,
    float* __restrict__ hinit)
{
    int gid = blockIdx.x * 256 + threadIdx.x;      // 131072
    long ch = gid >> 4;
    int n = gid & 15;
    long base = ch * (NCH * 16) + n;
    float h = 0.f;
    for (int c = 0; c < NCH; ++c) {
        hinit[base + c * 16] = h;
        h = Pbuf[base + c * 16] * h + hloc[base + c * 16];
    }
}

// ---------------- merge + LayerNorm + gate ----------------
__global__ __launch_bounds__(256) void ln_gate(
    const u16* __restrict__ ys_bf, const u16* __restrict__ z_bf,
    const float* __restrict__ ln_w, const float* __restrict__ ln_b,
    u16* __restrict__ yln)
{
    const int row = blockIdx.x;
    const int tid = threadIdx.x;
    const long b0 = (long)row * 1024;
    float v0 = bf2f(ys_bf[b0 + tid])       + bf2f(ys_bf[b0 + 512 + tid]);
    float v1 = bf2f(ys_bf[b0 + 256 + tid]) + bf2f(ys_bf[b0 + 768 + tid]);
    float s = v0 + v1;
    float q = v0 * v0 + v1 * v1;
    __shared__ float red[8];
    const int wv = tid >> 6, ln = tid & 63;
    #pragma unroll
    for (int off = 32; off > 0; off >>= 1) {
        s += __shfl_down(s, off);
        q += __shfl_down(q, off);
    }
    if (ln == 0) { red[wv] = s; red[4 + wv] = q; }
    __syncthreads();
    if (tid == 0) {
        float S = red[0] + red[1] + red[2] + red[3];
        float Q = red[4] + red[5] + red[6] + red[7];
        float mu = S * (1.f / 512.f);
        float var = Q * (1.f / 512.f) - mu * mu;
        red[0] = mu;
        red[1] = rsqrtf(var + 1e-5f);
    }
    __syncthreads();
    const float mu = red[0], rstd = red[1];
    const long zb = (long)row * 512;
    float o0 = (v0 - mu) * rstd * ln_w[tid] + ln_b[tid];
    float o1 = (v1 - mu) * rstd * ln_w[tid + 256] + ln_b[tid + 256];
    yln[zb + tid]       = f2bf(o0 * bf2f(z_bf[zb + tid]));
    yln[zb + 256 + tid] = f2bf(o1 * bf2f(z_bf[zb + 256 + tid]));
}

// ---------------- host launcher ----------------
extern "C" void kernel_launch(void* const* d_in, const int* in_sizes, int n_in,
                              void* d_out, int out_size, void* d_ws, size_t ws_size,
                              hipStream_t stream)
{
    const float* x      = (const float*)d_in[0];
    const float* W_in   = (const float*)d_in[1];
    const float* conv_w = (const float*)d_in[2];
    const float* conv_b = (const float*)d_in[3];
    const float* xpw    = (const float*)d_in[4];
    const float* dt_w   = (const float*)d_in[5];
    const float* dt_b   = (const float*)d_in[6];
    const float* A_logs = (const float*)d_in[7];
    const float* Ds     = (const float*)d_in[8];
    const float* ln_w   = (const float*)d_in[9];
    const float* ln_b   = (const float*)d_in[10];
    const float* W_out  = (const float*)d_in[11];

    char* w = (char*)d_ws;
    u16*   x_bf   = (u16*)  (w + 0);            // 16,777,216
    u16*   xx_bf  = (u16*)  (w + 16777216);     // 33,554,432
    u16*   z_bf   = (u16*)  (w + 50331648);     // 33,554,432
    u16*   u_bf   = (u16*)  (w + 83886080);     // 33,554,432
    u16*   yln_bf = (u16*)  (w + 117440512);    // 33,554,432
    u16*   win_bf = (u16*)  (w + 150994944);    // 524,288
    u16*   cw_bf  = (u16*)  (w + 151519232);    // 524,288
    u16*   xp_bf  = (u16*)  (w + 152043520);    // 98,304
    u16*   wo_bf  = (u16*)  (w + 152141824);    // 262,144
    float* Af     = (float*)(w + 152403968);    // 65,536
    float* proj   = (float*)(w + 152469504);    // 12,582,912
    u16*   ys_bf  = (u16*)  (w + 165052416);    // 33,554,432
    float* Pbuf   = (float*)(w + 198606848);    // 16,777,216
    float* hloc   = (float*)(w + 215384064);    // 16,777,216
    float* hinit  = (float*)(w + 232161280);    // 16,777,216
    // total: 248,938,496 bytes

    prep_kernel<<<35584, 256, 0, stream>>>(x, W_in, conv_w, xpw, W_out, A_logs,
                                           x_bf, win_bf, cw_bf, xp_bf, wo_bf, Af);

    // in_proj: [32768,256] @ [1024,256]^T
    gemm128<0><<<dim3(8, 256), 256, 0, stream>>>(x_bf, win_bf, 256, nullptr, xx_bf, z_bf, nullptr);
    // conv1x1 + bias + silu: [32768,512] @ [512,512]^T
    gemm128<1><<<dim3(4, 256), 256, 0, stream>>>(xx_bf, cw_bf, 512, conv_b, u_bf, nullptr, nullptr);
    // x_proj: [32768,512] @ [96,512]^T
    xproj_gemm<<<512, 256, 0, stream>>>(u_bf, xp_bf, proj);

    // scan
    scan_pass<0><<<1024, 256, 0, stream>>>(u_bf, proj, Af, dt_w, dt_b, Ds,
                                           Pbuf, hloc, nullptr, nullptr);
    scan_pass2<<<512, 256, 0, stream>>>(Pbuf, hloc, hinit);
    scan_pass<1><<<1024, 256, 0, stream>>>(u_bf, proj, Af, dt_w, dt_b, Ds,
                                           nullptr, nullptr, hinit, ys_bf);

    // merge + LN + gate
    ln_gate<<<32768, 256, 0, stream>>>(ys_bf, z_bf, ln_w, ln_b, yln_bf);
    // out_proj: [32768,512] @ [256,512]^T -> d_out
    gemm128<2><<<dim3(2, 256), 256, 0, stream>>>(yln_bf, wo_bf, 512, nullptr, nullptr, nullptr, (float*)d_out);
}

// Round 4
// 642.109 us; speedup vs baseline: 1.1149x; 1.0219x over previous
//
#include <hip/hip_runtime.h>

typedef unsigned short u16;
typedef __attribute__((ext_vector_type(8))) short s16x8;   // 8 bf16 in 4 VGPRs
typedef __attribute__((ext_vector_type(4))) float f32x4;

#define L_SEQ 4096
#define NB    8
#define DIM_  256
#define DI_   512
#define NST   16
#define RLOW  16
#define NCH   32     // chunks
#define CHL   128    // steps per chunk

__device__ __forceinline__ u16 f2bf(float f) {
    unsigned u = __float_as_uint(f);
    unsigned r = u + 0x7fffu + ((u >> 16) & 1u);
    return (u16)(r >> 16);
}
__device__ __forceinline__ float bf2f(u16 h) {
    return __uint_as_float(((unsigned)h) << 16);
}
__device__ __forceinline__ float silu_f(float x) { return x / (1.f + __expf(-x)); }
__device__ __forceinline__ float softplus_f(float x) {
    return (x > 20.f) ? x : __logf(1.f + __expf(x));
}

// ---------------- prep: cast inputs to bf16, precompute A*log2e ----------------
__global__ __launch_bounds__(256) void prep_kernel(
    const float* __restrict__ x, const float* __restrict__ Win,
    const float* __restrict__ cw, const float* __restrict__ xpw,
    const float* __restrict__ Wout, const float* __restrict__ Al,
    u16* __restrict__ xbf, u16* __restrict__ winbf, u16* __restrict__ cwbf,
    u16* __restrict__ xpbf, u16* __restrict__ wobf, float* __restrict__ Af)
{
    long i = (long)blockIdx.x * 256 + threadIdx.x;
    if (i < 8388608)  { xbf[i]  = f2bf(x[i]);   return; }  i -= 8388608;
    if (i < 262144)   { winbf[i] = f2bf(Win[i]); return; }  i -= 262144;
    if (i < 262144)   { cwbf[i] = f2bf(cw[i]);  return; }  i -= 262144;
    if (i < 49152)    { xpbf[i] = f2bf(xpw[i]); return; }  i -= 49152;
    if (i < 131072)   { wobf[i] = f2bf(Wout[i]); return; } i -= 131072;
    if (i < 16384)    { Af[i] = -__expf(Al[i]) * 1.4426950408889634f; }
}

// ---------------- big GEMM: C[M,N] = A[M,K] @ W[N,K]^T, bf16 MFMA ----------------
template<int EPI>
__global__ __launch_bounds__(256, 2) void gemm128(
    const u16* __restrict__ A, const u16* __restrict__ W, int Kd,
    const float* __restrict__ bias,
    u16* __restrict__ ob0, u16* __restrict__ ob1, float* __restrict__ of)
{
    const int m0 = blockIdx.y * 128;
    const int n0 = blockIdx.x * 128;
    const int tid = threadIdx.x;
    const int wave = tid >> 6, lane = tid & 63;
    const int wr = wave >> 1, wc = wave & 1;
    __shared__ __align__(16) u16 As[128 * 40];
    __shared__ __align__(16) u16 Bs[128 * 40];
    f32x4 acc[4][4] = {};
    const int lrow = tid >> 2;
    const int lk = (tid & 3) * 8;
    const int lm = lane & 15, lq = (lane >> 4) * 8;
    for (int k0 = 0; k0 < Kd; k0 += 32) {
        __syncthreads();
        #pragma unroll
        for (int cc = 0; cc < 2; ++cc) {
            int r = lrow + cc * 64;
            *(s16x8*)&As[r * 40 + lk] = *(const s16x8*)&A[(long)(m0 + r) * Kd + k0 + lk];
            *(s16x8*)&Bs[r * 40 + lk] = *(const s16x8*)&W[(long)(n0 + r) * Kd + k0 + lk];
        }
        __syncthreads();
        s16x8 aF[4], bF[4];
        #pragma unroll
        for (int it = 0; it < 4; ++it)
            aF[it] = *(const s16x8*)&As[(wr * 64 + it * 16 + lm) * 40 + lq];
        #pragma unroll
        for (int jt = 0; jt < 4; ++jt)
            bF[jt] = *(const s16x8*)&Bs[(wc * 64 + jt * 16 + lm) * 40 + lq];
        #pragma unroll
        for (int it = 0; it < 4; ++it)
            #pragma unroll
            for (int jt = 0; jt < 4; ++jt)
                acc[it][jt] = __builtin_amdgcn_mfma_f32_16x16x32_bf16(aF[it], bF[jt], acc[it][jt], 0, 0, 0);
    }
    const int lq4 = (lane >> 4) * 4;
    #pragma unroll
    for (int it = 0; it < 4; ++it)
        #pragma unroll
        for (int jt = 0; jt < 4; ++jt)
            #pragma unroll
            for (int r = 0; r < 4; ++r) {
                int row = m0 + wr * 64 + it * 16 + lq4 + r;
                int col = n0 + wc * 64 + jt * 16 + lm;
                float v = acc[it][jt][r];
                if (EPI == 0) {
                    if (col < 512) ob0[(long)row * 512 + col] = f2bf(v);
                    else           ob1[(long)row * 512 + (col - 512)] = f2bf(silu_f(v));
                } else if (EPI == 1) {
                    v += bias[col];
                    ob0[(long)row * 512 + col] = f2bf(silu_f(v));
                } else {
                    of[(long)row * 256 + col] = v;
                }
            }
}

// ---------------- x_proj GEMM: proj[M,96] = u[M,512] @ xpw[96,512]^T ----------------
__global__ __launch_bounds__(256, 4) void xproj_gemm(
    const u16* __restrict__ u_bf, const u16* __restrict__ xpw,
    float* __restrict__ proj)
{
    const int wave = threadIdx.x >> 6, lane = threadIdx.x & 63;
    const int m0 = blockIdx.x * 64 + wave * 16;
    const int lm = lane & 15, lq = (lane >> 4) * 8;
    f32x4 acc[6] = {};
    for (int k0 = 0; k0 < 512; k0 += 32) {
        s16x8 aF = *(const s16x8*)&u_bf[(long)(m0 + lm) * 512 + k0 + lq];
        #pragma unroll
        for (int jt = 0; jt < 6; ++jt) {
            s16x8 bF = *(const s16x8*)&xpw[(long)(jt * 16 + lm) * 512 + k0 + lq];
            acc[jt] = __builtin_amdgcn_mfma_f32_16x16x32_bf16(aF, bF, acc[jt], 0, 0, 0);
        }
    }
    const int lq4 = (lane >> 4) * 4;
    #pragma unroll
    for (int jt = 0; jt < 6; ++jt)
        #pragma unroll
        for (int r = 0; r < 4; ++r)
            proj[(long)(m0 + lq4 + r) * 96 + jt * 16 + lm] = acc[jt][r];
}

// ---------------- chunked selective scan ----------------
// PASS 0: local scan from h=0; records sum(delta) -> P[n]=exp2(A[n]*sum) and end state.
// PASS 1: replay with true initial state (hinit), emit y per token.
// The chunk's proj rows are bulk-staged into LDS once (coalesced global reads),
// then the step loop does broadcast ds_read_b128 (lane-uniform addr) — no
// per-step SMEM/global latency. u is register double-buffered.
template<int PASS>
__global__ __launch_bounds__(256) __attribute__((amdgpu_waves_per_eu(4, 4)))
void scan_pass(
    const u16* __restrict__ u_bf, const float* __restrict__ proj,
    const float* __restrict__ Af, const float* __restrict__ dtw_g,
    const float* __restrict__ dtb_g, const float* __restrict__ Ds,
    float* __restrict__ Pbuf, float* __restrict__ hloc,
    const float* __restrict__ hinit, u16* __restrict__ ys_bf)
{
    const int bid = blockIdx.x;
    const int c  = bid & (NCH - 1);
    const int t2 = bid >> 5;
    const int dh = t2 & 1;
    const int bk = t2 >> 1;            // b*2+k
    const int k = bk & 1, b = bk >> 1;
    const int d = dh * 256 + threadIdx.x;
    const int kd = k * 512 + d;
    const long ch = (long)bk * 512 + d;

    constexpr int PW = (PASS == 0) ? 32 : 48;       // floats staged per step
    constexpr int NX4 = PW / 4;
    __shared__ __align__(16) float lds_p[CHL * PW];

    const int t0 = c * CHL;
    const int m0r = k ? (L_SEQ - 1 - t0) : t0;
    const int stp = k ? -1 : 1;
    const long row0 = (long)b * L_SEQ + m0r;

    // ---- bulk stage proj chunk into LDS ----
    {
        const float* pbase = proj + row0 * 96 + k * 48;
        const long prstep = (long)stp * 96;
        #pragma unroll
        for (int it = threadIdx.x; it < CHL * NX4; it += 256) {
            int s = it / NX4, j = it - s * NX4;
            f32x4 v = *(const f32x4*)(pbase + prstep * s + j * 4);
            *(f32x4*)&lds_p[s * PW + j * 4] = v;
        }
    }

    // ---- per-channel constants ----
    f32x4 A2[4], dtw[4], h[4];
    {
        const f32x4* Ap = (const f32x4*)(Af + (long)kd * 16);
        const f32x4* Wp = (const f32x4*)(dtw_g + (long)kd * 16);
        #pragma unroll
        for (int i = 0; i < 4; ++i) { A2[i] = Ap[i]; dtw[i] = Wp[i]; }
    }
    const float dtb = dtb_g[kd];
    float Dv = 0.f;
    float sdelta = 0.f;
    if (PASS == 0) {
        #pragma unroll
        for (int i = 0; i < 4; ++i) h[i] = (f32x4){0.f, 0.f, 0.f, 0.f};
    } else {
        Dv = Ds[kd];
        const f32x4* Hp = (const f32x4*)(hinit + ch * (NCH * 16) + c * 16);
        #pragma unroll
        for (int i = 0; i < 4; ++i) h[i] = Hp[i];
    }

    const u16* up = u_bf + row0 * 512 + d;
    u16* yp = (PASS == 1) ? (ys_bf + row0 * 1024 + (long)k * 512 + d) : nullptr;
    const long ustep = (long)stp * 512;
    const long ystep = (long)stp * 1024;

    __syncthreads();

    float u_next = bf2f(*up);
    up += ustep;

    for (int s = 0; s < CHL; ++s) {
        const float* Ls = &lds_p[s * PW];
        // dt-section
        f32x4 pd[4];
        #pragma unroll
        for (int i = 0; i < 4; ++i) pd[i] = *(const f32x4*)&Ls[i * 4];
        float uu = u_next;
        if (s + 1 < CHL) { u_next = bf2f(*up); up += ustep; }
        float dt = dtb;
        #pragma unroll
        for (int i = 0; i < 4; ++i)
            #pragma unroll
            for (int j = 0; j < 4; ++j)
                dt = fmaf(pd[i][j], dtw[i][j], dt);
        float delta = softplus_f(dt);
        float du = delta * uu;
        // B-section
        f32x4 pb[4];
        #pragma unroll
        for (int i = 0; i < 4; ++i) pb[i] = *(const f32x4*)&Ls[16 + i * 4];
        if (PASS == 0) {
            sdelta += delta;
            #pragma unroll
            for (int i = 0; i < 4; ++i)
                #pragma unroll
                for (int j = 0; j < 4; ++j) {
                    float a = exp2f(delta * A2[i][j]);
                    h[i][j] = fmaf(a, h[i][j], du * pb[i][j]);
                }
        } else {
            f32x4 pc[4];
            #pragma unroll
            for (int i = 0; i < 4; ++i) pc[i] = *(const f32x4*)&Ls[32 + i * 4];
            float y = 0.f;
            #pragma unroll
            for (int i = 0; i < 4; ++i)
                #pragma unroll
                for (int j = 0; j < 4; ++j) {
                    float a = exp2f(delta * A2[i][j]);
                    float hv = fmaf(a, h[i][j], du * pb[i][j]);
                    h[i][j] = hv;
                    y = fmaf(hv, pc[i][j], y);
                }
            y = fmaf(Dv, uu, y);
            *yp = f2bf(y);
            yp += ystep;
        }
    }
    if (PASS == 0) {
        f32x4* Pp = (f32x4*)(Pbuf + ch * (NCH * 16) + c * 16);
        f32x4* Hp = (f32x4*)(hloc + ch * (NCH * 16) + c * 16);
        #pragma unroll
        for (int i = 0; i < 4; ++i) {
            f32x4 pe;
            #pragma unroll
            for (int j = 0; j < 4; ++j) pe[j] = exp2f(A2[i][j] * sdelta);
            Pp[i] = pe;
            Hp[i] = h[i];
        }
    }
}

// pass 2: chain the chunk summaries. thread = (channel, n)
__global__ __launch_bounds__(256) void scan_pass2(
    const float* __restrict__ Pbuf, const float* __restrict__ hloc,
    float* __restrict__ hinit)
{
    int gid = blockIdx.x * 256 + threadIdx.x;      // 131072
    long ch = gid >> 4;
    int n = gid & 15;
    long base = ch * (NCH * 16) + n;
    float h = 0.f;
    for (int c = 0; c < NCH; ++c) {
        hinit[base + c * 16] = h;
        h = Pbuf[base + c * 16] * h + hloc[base + c * 16];
    }
}

// ---------------- merge + LayerNorm + gate ----------------
__global__ __launch_bounds__(256) void ln_gate(
    const u16* __restrict__ ys_bf, const u16* __restrict__ z_bf,
    const float* __restrict__ ln_w, const float* __restrict__ ln_b,
    u16* __restrict__ yln)
{
    const int row = blockIdx.x;
    const int tid = threadIdx.x;
    const long b0 = (long)row * 1024;
    float v0 = bf2f(ys_bf[b0 + tid])       + bf2f(ys_bf[b0 + 512 + tid]);
    float v1 = bf2f(ys_bf[b0 + 256 + tid]) + bf2f(ys_bf[b0 + 768 + tid]);
    float s = v0 + v1;
    float q = v0 * v0 + v1 * v1;
    __shared__ float red[8];
    const int wv = tid >> 6, ln = tid & 63;
    #pragma unroll
    for (int off = 32; off > 0; off >>= 1) {
        s += __shfl_down(s, off);
        q += __shfl_down(q, off);
    }
    if (ln == 0) { red[wv] = s; red[4 + wv] = q; }
    __syncthreads();
    if (tid == 0) {
        float S = red[0] + red[1] + red[2] + red[3];
        float Q = red[4] + red[5] + red[6] + red[7];
        float mu = S * (1.f / 512.f);
        float var = Q * (1.f / 512.f) - mu * mu;
        red[0] = mu;
        red[1] = rsqrtf(var + 1e-5f);
    }
    __syncthreads();
    const float mu = red[0], rstd = red[1];
    const long zb = (long)row * 512;
    float o0 = (v0 - mu) * rstd * ln_w[tid] + ln_b[tid];
    float o1 = (v1 - mu) * rstd * ln_w[tid + 256] + ln_b[tid + 256];
    yln[zb + tid]       = f2bf(o0 * bf2f(z_bf[zb + tid]));
    yln[zb + 256 + tid] = f2bf(o1 * bf2f(z_bf[zb + 256 + tid]));
}

// ---------------- host launcher ----------------
extern "C" void kernel_launch(void* const* d_in, const int* in_sizes, int n_in,
                              void* d_out, int out_size, void* d_ws, size_t ws_size,
                              hipStream_t stream)
{
    const float* x      = (const float*)d_in[0];
    const float* W_in   = (const float*)d_in[1];
    const float* conv_w = (const float*)d_in[2];
    const float* conv_b = (const float*)d_in[3];
    const float* xpw    = (const float*)d_in[4];
    const float* dt_w   = (const float*)d_in[5];
    const float* dt_b   = (const float*)d_in[6];
    const float* A_logs = (const float*)d_in[7];
    const float* Ds     = (const float*)d_in[8];
    const float* ln_w   = (const float*)d_in[9];
    const float* ln_b   = (const float*)d_in[10];
    const float* W_out  = (const float*)d_in[11];

    char* w = (char*)d_ws;
    u16*   x_bf   = (u16*)  (w + 0);            // 16,777,216
    u16*   xx_bf  = (u16*)  (w + 16777216);     // 33,554,432
    u16*   z_bf   = (u16*)  (w + 50331648);     // 33,554,432
    u16*   u_bf   = (u16*)  (w + 83886080);     // 33,554,432
    u16*   yln_bf = (u16*)  (w + 117440512);    // 33,554,432
    u16*   win_bf = (u16*)  (w + 150994944);    // 524,288
    u16*   cw_bf  = (u16*)  (w + 151519232);    // 524,288
    u16*   xp_bf  = (u16*)  (w + 152043520);    // 98,304
    u16*   wo_bf  = (u16*)  (w + 152141824);    // 262,144
    float* Af     = (float*)(w + 152403968);    // 65,536
    float* proj   = (float*)(w + 152469504);    // 12,582,912
    u16*   ys_bf  = (u16*)  (w + 165052416);    // 33,554,432
    float* Pbuf   = (float*)(w + 198606848);    // 16,777,216
    float* hloc   = (float*)(w + 215384064);    // 16,777,216
    float* hinit  = (float*)(w + 232161280);    // 16,777,216
    // total: 248,938,496 bytes

    prep_kernel<<<35584, 256, 0, stream>>>(x, W_in, conv_w, xpw, W_out, A_logs,
                                           x_bf, win_bf, cw_bf, xp_bf, wo_bf, Af);

    // in_proj: [32768,256] @ [1024,256]^T
    gemm128<0><<<dim3(8, 256), 256, 0, stream>>>(x_bf, win_bf, 256, nullptr, xx_bf, z_bf, nullptr);
    // conv1x1 + bias + silu: [32768,512] @ [512,512]^T
    gemm128<1><<<dim3(4, 256), 256, 0, stream>>>(xx_bf, cw_bf, 512, conv_b, u_bf, nullptr, nullptr);
    // x_proj: [32768,512] @ [96,512]^T
    xproj_gemm<<<512, 256, 0, stream>>>(u_bf, xp_bf, proj);

    // scan
    scan_pass<0><<<1024, 256, 0, stream>>>(u_bf, proj, Af, dt_w, dt_b, Ds,
                                           Pbuf, hloc, nullptr, nullptr);
    scan_pass2<<<512, 256, 0, stream>>>(Pbuf, hloc, hinit);
    scan_pass<1><<<1024, 256, 0, stream>>>(u_bf, proj, Af, dt_w, dt_b, Ds,
                                           nullptr, nullptr, hinit, ys_bf);

    // merge + LN + gate
    ln_gate<<<32768, 256, 0, stream>>>(ys_bf, z_bf, ln_w, ln_b, yln_bf);
    // out_proj: [32768,512] @ [256,512]^T -> d_out
    gemm128<2><<<dim3(2, 256), 256, 0, stream>>>(yln_bf, wo_bf, 512, nullptr, nullptr, nullptr, (float*)d_out);
}

// Round 6
// 480.055 us; speedup vs baseline: 1.4912x; 1.3376x over previous
//
#include <hip/hip_runtime.h>

typedef unsigned short u16;
typedef __attribute__((ext_vector_type(8))) short s16x8;   // 8 bf16 in 4 VGPRs
typedef __attribute__((ext_vector_type(4))) float f32x4;

#define L_SEQ 4096
#define NB    8
#define DIM_  256
#define DI_   512
#define NST   16
#define RLOW  16
#define NCH   32     // chunks
#define CHL   128    // steps per chunk

__device__ __forceinline__ u16 f2bf(float f) {
    unsigned u = __float_as_uint(f);
    unsigned r = u + 0x7fffu + ((u >> 16) & 1u);
    return (u16)(r >> 16);
}
__device__ __forceinline__ float bf2f(u16 h) {
    return __uint_as_float(((unsigned)h) << 16);
}
__device__ __forceinline__ float silu_f(float x) { return x / (1.f + __expf(-x)); }
__device__ __forceinline__ float softplus_f(float x) {
    return (x > 20.f) ? x : __logf(1.f + __expf(x));
}
__device__ __forceinline__ float fexp2(float x) { return __builtin_amdgcn_exp2f(x); }

// ---------------- prep: cast inputs to bf16, precompute A*log2e ----------------
__global__ __launch_bounds__(256) void prep_kernel(
    const float* __restrict__ x, const float* __restrict__ Win,
    const float* __restrict__ cw, const float* __restrict__ xpw,
    const float* __restrict__ Wout, const float* __restrict__ dtw,
    const float* __restrict__ Al,
    u16* __restrict__ xbf, u16* __restrict__ winbf, u16* __restrict__ cwbf,
    u16* __restrict__ xpbf, u16* __restrict__ wobf, u16* __restrict__ dtwbf,
    float* __restrict__ Af)
{
    long i = (long)blockIdx.x * 256 + threadIdx.x;
    if (i < 8388608)  { xbf[i]  = f2bf(x[i]);   return; }  i -= 8388608;
    if (i < 262144)   { winbf[i] = f2bf(Win[i]); return; }  i -= 262144;
    if (i < 262144)   { cwbf[i] = f2bf(cw[i]);  return; }  i -= 262144;
    if (i < 49152)    { xpbf[i] = f2bf(xpw[i]); return; }  i -= 49152;
    if (i < 131072)   { wobf[i] = f2bf(Wout[i]); return; } i -= 131072;
    if (i < 16384)    { dtwbf[i] = f2bf(dtw[i]); return; } i -= 16384;
    if (i < 16384)    { Af[i] = -__expf(Al[i]) * 1.4426950408889634f; }
}

// ---------------- big GEMM: C[M,N] = A[M,K] @ W[N,K]^T, bf16 MFMA ----------------
template<int EPI>
__global__ __launch_bounds__(256, 2) void gemm128(
    const u16* __restrict__ A, const u16* __restrict__ W, int Kd,
    const float* __restrict__ bias,
    u16* __restrict__ ob0, u16* __restrict__ ob1, float* __restrict__ of)
{
    const int m0 = blockIdx.y * 128;
    const int n0 = blockIdx.x * 128;
    const int tid = threadIdx.x;
    const int wave = tid >> 6, lane = tid & 63;
    const int wr = wave >> 1, wc = wave & 1;
    __shared__ __align__(16) u16 As[128 * 40];
    __shared__ __align__(16) u16 Bs[128 * 40];
    f32x4 acc[4][4] = {};
    const int lrow = tid >> 2;
    const int lk = (tid & 3) * 8;
    const int lm = lane & 15, lq = (lane >> 4) * 8;
    for (int k0 = 0; k0 < Kd; k0 += 32) {
        __syncthreads();
        #pragma unroll
        for (int cc = 0; cc < 2; ++cc) {
            int r = lrow + cc * 64;
            *(s16x8*)&As[r * 40 + lk] = *(const s16x8*)&A[(long)(m0 + r) * Kd + k0 + lk];
            *(s16x8*)&Bs[r * 40 + lk] = *(const s16x8*)&W[(long)(n0 + r) * Kd + k0 + lk];
        }
        __syncthreads();
        s16x8 aF[4], bF[4];
        #pragma unroll
        for (int it = 0; it < 4; ++it)
            aF[it] = *(const s16x8*)&As[(wr * 64 + it * 16 + lm) * 40 + lq];
        #pragma unroll
        for (int jt = 0; jt < 4; ++jt)
            bF[jt] = *(const s16x8*)&Bs[(wc * 64 + jt * 16 + lm) * 40 + lq];
        #pragma unroll
        for (int it = 0; it < 4; ++it)
            #pragma unroll
            for (int jt = 0; jt < 4; ++jt)
                acc[it][jt] = __builtin_amdgcn_mfma_f32_16x16x32_bf16(aF[it], bF[jt], acc[it][jt], 0, 0, 0);
    }
    const int lq4 = (lane >> 4) * 4;
    #pragma unroll
    for (int it = 0; it < 4; ++it)
        #pragma unroll
        for (int jt = 0; jt < 4; ++jt)
            #pragma unroll
            for (int r = 0; r < 4; ++r) {
                int row = m0 + wr * 64 + it * 16 + lq4 + r;
                int col = n0 + wc * 64 + jt * 16 + lm;
                float v = acc[it][jt][r];
                if (EPI == 0) {
                    if (col < 512) ob0[(long)row * 512 + col] = f2bf(v);
                    else           ob1[(long)row * 512 + (col - 512)] = f2bf(silu_f(v));
                } else if (EPI == 1) {
                    v += bias[col];
                    ob0[(long)row * 512 + col] = f2bf(silu_f(v));
                } else {
                    of[(long)row * 256 + col] = v;
                }
            }
}

// ---------------- x_proj GEMM: proj[M,96] = u[M,512] @ xpw[96,512]^T ----------------
__global__ __launch_bounds__(256, 4) void xproj_gemm(
    const u16* __restrict__ u_bf, const u16* __restrict__ xpw,
    float* __restrict__ proj)
{
    const int wave = threadIdx.x >> 6, lane = threadIdx.x & 63;
    const int m0 = blockIdx.x * 64 + wave * 16;
    const int lm = lane & 15, lq = (lane >> 4) * 8;
    f32x4 acc[6] = {};
    for (int k0 = 0; k0 < 512; k0 += 32) {
        s16x8 aF = *(const s16x8*)&u_bf[(long)(m0 + lm) * 512 + k0 + lq];
        #pragma unroll
        for (int jt = 0; jt < 6; ++jt) {
            s16x8 bF = *(const s16x8*)&xpw[(long)(jt * 16 + lm) * 512 + k0 + lq];
            acc[jt] = __builtin_amdgcn_mfma_f32_16x16x32_bf16(aF, bF, acc[jt], 0, 0, 0);
        }
    }
    const int lq4 = (lane >> 4) * 4;
    #pragma unroll
    for (int jt = 0; jt < 6; ++jt)
        #pragma unroll
        for (int r = 0; r < 4; ++r)
            proj[(long)(m0 + lq4 + r) * 96 + jt * 16 + lm] = acc[jt][r];
}

// ---------------- delta GEMM: delta[row][k][d] = softplus(dts[row][k]·dt_w[k][d] + dt_b[k][d]) ----
// M=32768 rows, N=512 d, K=16 r (zero-padded to MFMA K=32). Output bf16.
__global__ __launch_bounds__(256, 4) void delta_gemm(
    const float* __restrict__ proj, const u16* __restrict__ dtw_bf,
    const float* __restrict__ dtb_g, u16* __restrict__ delta_bf)
{
    const int kk = blockIdx.z;            // direction
    const int n0 = blockIdx.x * 128;      // d tile
    const int m0 = blockIdx.y * 64;       // row tile
    const int wave = threadIdx.x >> 6, lane = threadIdx.x & 63;
    const int lm = lane & 15, lq = (lane >> 4) * 8;
    const int mrow = m0 + wave * 16 + lm;

    // A fragment: dts[mrow][r=lq..lq+7]; zero for lq>=16 (K padding)
    s16x8 aF = (s16x8){0, 0, 0, 0, 0, 0, 0, 0};
    if (lq < 16) {
        const float* pr = proj + (long)mrow * 96 + kk * 48 + lq;
        f32x4 p0 = *(const f32x4*)pr;
        f32x4 p1 = *(const f32x4*)(pr + 4);
        #pragma unroll
        for (int j = 0; j < 4; ++j) {
            ((short*)&aF)[j]     = (short)f2bf(p0[j]);
            ((short*)&aF)[4 + j] = (short)f2bf(p1[j]);
        }
    }

    f32x4 acc[8];
    #pragma unroll
    for (int jt = 0; jt < 8; ++jt) {
        int dcol = n0 + jt * 16 + lm;
        s16x8 bF = (s16x8){0, 0, 0, 0, 0, 0, 0, 0};
        if (lq < 16)
            bF = *(const s16x8*)&dtw_bf[((long)kk * 512 + dcol) * 16 + lq];
        acc[jt] = __builtin_amdgcn_mfma_f32_16x16x32_bf16(aF, bF, (f32x4){0.f, 0.f, 0.f, 0.f}, 0, 0, 0);
    }
    const int lq4 = (lane >> 4) * 4;
    #pragma unroll
    for (int jt = 0; jt < 8; ++jt) {
        int dcol = n0 + jt * 16 + lm;
        float bias = dtb_g[kk * 512 + dcol];
        #pragma unroll
        for (int r = 0; r < 4; ++r) {
            int row = m0 + wave * 16 + lq4 + r;
            float v = acc[jt][r] + bias;
            delta_bf[(long)row * 1024 + kk * 512 + dcol] = f2bf(softplus_f(v));
        }
    }
}

// ---------------- chunked selective scan ----------------
// delta precomputed (delta_gemm); B (and C for PASS1) staged in LDS per chunk;
// delta/u register-prefetched; exp2 via raw v_exp_f32.
template<int PASS>
__global__ __launch_bounds__(256) __attribute__((amdgpu_waves_per_eu(4, 4)))
void scan_pass(
    const u16* __restrict__ u_bf, const u16* __restrict__ delta_bf,
    const float* __restrict__ proj,
    const float* __restrict__ Af, const float* __restrict__ Ds,
    float* __restrict__ Pbuf, float* __restrict__ hloc,
    const float* __restrict__ hinit, u16* __restrict__ ys_bf)
{
    const int bid = blockIdx.x;
    const int c  = bid & (NCH - 1);
    const int t2 = bid >> 5;
    const int dh = t2 & 1;
    const int bk = t2 >> 1;            // b*2+k
    const int k = bk & 1, b = bk >> 1;
    const int d = dh * 256 + threadIdx.x;
    const int kd = k * 512 + d;
    const long ch = (long)bk * 512 + d;

    constexpr int PW = (PASS == 0) ? 16 : 32;       // floats staged per step
    constexpr int NX4 = PW / 4;
    constexpr int LG = (PASS == 0) ? 2 : 3;
    __shared__ __align__(16) float lds_p[CHL * PW];

    const int t0 = c * CHL;
    const int m0r = k ? (L_SEQ - 1 - t0) : t0;
    const int stp = k ? -1 : 1;
    const long row0 = (long)b * L_SEQ + m0r;

    // ---- bulk stage B (and C) sections into LDS ----
    {
        const float* pbase = proj + row0 * 96 + k * 48 + 16;
        const long prstep = (long)stp * 96;
        #pragma unroll
        for (int it = threadIdx.x; it < CHL * NX4; it += 256) {
            int s = it >> LG, j = it & (NX4 - 1);
            f32x4 v = *(const f32x4*)(pbase + prstep * s + j * 4);
            *(f32x4*)&lds_p[s * PW + j * 4] = v;
        }
    }

    // ---- per-channel constants ----
    f32x4 A2[4], h[4];
    {
        const f32x4* Ap = (const f32x4*)(Af + (long)kd * 16);
        #pragma unroll
        for (int i = 0; i < 4; ++i) A2[i] = Ap[i];
    }
    float Dv = 0.f;
    float sdelta = 0.f;
    if (PASS == 0) {
        #pragma unroll
        for (int i = 0; i < 4; ++i) h[i] = (f32x4){0.f, 0.f, 0.f, 0.f};
    } else {
        Dv = Ds[kd];
        const f32x4* Hp = (const f32x4*)(hinit + ch * (NCH * 16) + c * 16);
        #pragma unroll
        for (int i = 0; i < 4; ++i) h[i] = Hp[i];
    }

    const u16* up = u_bf + row0 * 512 + d;
    const u16* dp = delta_bf + row0 * 1024 + kd;
    u16* yp = (PASS == 1) ? (ys_bf + row0 * 1024 + (long)k * 512 + d) : nullptr;
    const long ustep = (long)stp * 512;
    const long dstep = (long)stp * 1024;
    const long ystep = (long)stp * 1024;

    __syncthreads();

    float u_n = bf2f(*up);
    float de_n = bf2f(*dp);

    for (int s = 0; s < CHL; ++s) {
        float uu = u_n;
        float delta = de_n;
        if (s + 1 < CHL) {
            up += ustep; dp += dstep;
            u_n = bf2f(*up);
            de_n = bf2f(*dp);
        }
        const float* Ls = &lds_p[s * PW];
        f32x4 pb[4];
        #pragma unroll
        for (int i = 0; i < 4; ++i) pb[i] = *(const f32x4*)&Ls[i * 4];
        float du = delta * uu;
        if (PASS == 0) {
            sdelta += delta;
            #pragma unroll
            for (int i = 0; i < 4; ++i)
                #pragma unroll
                for (int j = 0; j < 4; ++j) {
                    float a = fexp2(delta * A2[i][j]);
                    h[i][j] = fmaf(a, h[i][j], du * pb[i][j]);
                }
        } else {
            f32x4 pc[4];
            #pragma unroll
            for (int i = 0; i < 4; ++i) pc[i] = *(const f32x4*)&Ls[16 + i * 4];
            float y = 0.f;
            #pragma unroll
            for (int i = 0; i < 4; ++i)
                #pragma unroll
                for (int j = 0; j < 4; ++j) {
                    float a = fexp2(delta * A2[i][j]);
                    float hv = fmaf(a, h[i][j], du * pb[i][j]);
                    h[i][j] = hv;
                    y = fmaf(hv, pc[i][j], y);
                }
            y = fmaf(Dv, uu, y);
            *yp = f2bf(y);
            yp += ystep;
        }
    }
    if (PASS == 0) {
        f32x4* Pp = (f32x4*)(Pbuf + ch * (NCH * 16) + c * 16);
        f32x4* Hp = (f32x4*)(hloc + ch * (NCH * 16) + c * 16);
        #pragma unroll
        for (int i = 0; i < 4; ++i) {
            f32x4 pe;
            #pragma unroll
            for (int j = 0; j < 4; ++j) pe[j] = fexp2(A2[i][j] * sdelta);
            Pp[i] = pe;
            Hp[i] = h[i];
        }
    }
}

// pass 2: chain the chunk summaries. thread = (channel, n)
__global__ __launch_bounds__(256) void scan_pass2(
    const float* __restrict__ Pbuf, const float* __restrict__ hloc,
    float* __restrict__ hinit)
{
    int gid = blockIdx.x * 256 + threadIdx.x;      // 131072
    long ch = gid >> 4;
    int n = gid & 15;
    long base = ch * (NCH * 16) + n;
    float h = 0.f;
    for (int c = 0; c < NCH; ++c) {
        hinit[base + c * 16] = h;
        h = Pbuf[base + c * 16] * h + hloc[base + c * 16];
    }
}

// ---------------- merge + LayerNorm + gate ----------------
__global__ __launch_bounds__(256) void ln_gate(
    const u16* __restrict__ ys_bf, const u16* __restrict__ z_bf,
    const float* __restrict__ ln_w, const float* __restrict__ ln_b,
    u16* __restrict__ yln)
{
    const int row = blockIdx.x;
    const int tid = threadIdx.x;
    const long b0 = (long)row * 1024;
    float v0 = bf2f(ys_bf[b0 + tid])       + bf2f(ys_bf[b0 + 512 + tid]);
    float v1 = bf2f(ys_bf[b0 + 256 + tid]) + bf2f(ys_bf[b0 + 768 + tid]);
    float s = v0 + v1;
    float q = v0 * v0 + v1 * v1;
    __shared__ float red[8];
    const int wv = tid >> 6, ln = tid & 63;
    #pragma unroll
    for (int off = 32; off > 0; off >>= 1) {
        s += __shfl_down(s, off);
        q += __shfl_down(q, off);
    }
    if (ln == 0) { red[wv] = s; red[4 + wv] = q; }
    __syncthreads();
    if (tid == 0) {
        float S = red[0] + red[1] + red[2] + red[3];
        float Q = red[4] + red[5] + red[6] + red[7];
        float mu = S * (1.f / 512.f);
        float var = Q * (1.f / 512.f) - mu * mu;
        red[0] = mu;
        red[1] = rsqrtf(var + 1e-5f);
    }
    __syncthreads();
    const float mu = red[0], rstd = red[1];
    const long zb = (long)row * 512;
    float o0 = (v0 - mu) * rstd * ln_w[tid] + ln_b[tid];
    float o1 = (v1 - mu) * rstd * ln_w[tid + 256] + ln_b[tid + 256];
    yln[zb + tid]       = f2bf(o0 * bf2f(z_bf[zb + tid]));
    yln[zb + 256 + tid] = f2bf(o1 * bf2f(z_bf[zb + 256 + tid]));
}

// ---------------- host launcher ----------------
extern "C" void kernel_launch(void* const* d_in, const int* in_sizes, int n_in,
                              void* d_out, int out_size, void* d_ws, size_t ws_size,
                              hipStream_t stream)
{
    const float* x      = (const float*)d_in[0];
    const float* W_in   = (const float*)d_in[1];
    const float* conv_w = (const float*)d_in[2];
    const float* conv_b = (const float*)d_in[3];
    const float* xpw    = (const float*)d_in[4];
    const float* dt_w   = (const float*)d_in[5];
    const float* dt_b   = (const float*)d_in[6];
    const float* A_logs = (const float*)d_in[7];
    const float* Ds     = (const float*)d_in[8];
    const float* ln_w   = (const float*)d_in[9];
    const float* ln_b   = (const float*)d_in[10];
    const float* W_out  = (const float*)d_in[11];

    // Lifetime-based layout (peak 232,194,048 B; proven budget >= 248,938,496 B).
    // Region 0..64MB time-shares: {x_bf, xx_bf} -> {Pbuf, hloc} -> ys (64MB!).
    // hinit is NEVER aliased (scan_pass<1> reads it while writing ys).
    // yln aliases u (dead after scan_pass<1>).
    char* w = (char*)d_ws;
    u16*   x_bf   = (u16*)  (w + 0);            // 16,777,216  [prep -> gemm0]
    u16*   xx_bf  = (u16*)  (w + 16777216);     // 33,554,432  [gemm0 -> gemm1]
    float* Pbuf   = (float*)(w + 0);            // 16,777,216  [scan0 -> pass2]
    float* hloc   = (float*)(w + 16777216);     // 16,777,216  [scan0 -> pass2]
    u16*   ys_bf  = (u16*)  (w + 0);            // 67,108,864  [scan1 -> ln_gate]
    float* hinit  = (float*)(w + 67108864);     // 16,777,216  [pass2 -> scan1]
    u16*   z_bf   = (u16*)  (w + 83886080);     // 33,554,432  [gemm0 -> ln_gate]
    u16*   u_bf   = (u16*)  (w + 117440512);    // 33,554,432  [gemm1 -> scan1]
    u16*   yln_bf = (u16*)  (w + 117440512);    // 33,554,432  [ln_gate -> gemm2] (aliases u)
    u16*   del_bf = (u16*)  (w + 150994944);    // 67,108,864  [delta_gemm -> scan1]
    float* proj   = (float*)(w + 218103808);    // 12,582,912  [xproj -> scan1]
    u16*   win_bf = (u16*)  (w + 230686720);    // 524,288
    u16*   cw_bf  = (u16*)  (w + 231211008);    // 524,288
    u16*   xp_bf  = (u16*)  (w + 231735296);    // 98,304
    u16*   wo_bf  = (u16*)  (w + 231833600);    // 262,144
    u16*   dtw_bf = (u16*)  (w + 232095744);    // 32,768
    float* Af     = (float*)(w + 232128512);    // 65,536   -> end 232,194,048

    prep_kernel<<<35648, 256, 0, stream>>>(x, W_in, conv_w, xpw, W_out, dt_w, A_logs,
                                           x_bf, win_bf, cw_bf, xp_bf, wo_bf, dtw_bf, Af);

    // in_proj: [32768,256] @ [1024,256]^T
    gemm128<0><<<dim3(8, 256), 256, 0, stream>>>(x_bf, win_bf, 256, nullptr, xx_bf, z_bf, nullptr);
    // conv1x1 + bias + silu: [32768,512] @ [512,512]^T
    gemm128<1><<<dim3(4, 256), 256, 0, stream>>>(xx_bf, cw_bf, 512, conv_b, u_bf, nullptr, nullptr);
    // x_proj: [32768,512] @ [96,512]^T
    xproj_gemm<<<512, 256, 0, stream>>>(u_bf, xp_bf, proj);
    // delta: softplus(dts @ dt_w^T + dt_b) -> bf16 [row][k][d]
    delta_gemm<<<dim3(4, 512, 2), 256, 0, stream>>>(proj, dtw_bf, dt_b, del_bf);

    // scan
    scan_pass<0><<<1024, 256, 0, stream>>>(u_bf, del_bf, proj, Af, Ds,
                                           Pbuf, hloc, nullptr, nullptr);
    scan_pass2<<<512, 256, 0, stream>>>(Pbuf, hloc, hinit);
    scan_pass<1><<<1024, 256, 0, stream>>>(u_bf, del_bf, proj, Af, Ds,
                                           nullptr, nullptr, hinit, ys_bf);

    // merge + LN + gate
    ln_gate<<<32768, 256, 0, stream>>>(ys_bf, z_bf, ln_w, ln_b, yln_bf);
    // out_proj: [32768,512] @ [256,512]^T -> d_out
    gemm128<2><<<dim3(2, 256), 256, 0, stream>>>(yln_bf, wo_bf, 512, nullptr, nullptr, nullptr, (float*)d_out);
}